// Round 3
// baseline (179.829 us; speedup 1.0000x reference)
//
// r14 — occupancy via smaller blocks, not reg caps.
// r12/r13 post-mortem: the 64-total-reg cap ALWAYS spills with 512-thread
// blocks (r13 still +22MB FETCH / +16MB WRITE of scratch; 71us > r11's 66).
// New route: MT=32, 256 threads, wave = 2 row-tiles x 4 col-tiles.
//  - acc stays 32 AGPR, arch ~40 -> ~72 total = r11's pressure (no spill)
//  - launch_bounds(256,6): cap ~84 regs -> 6 waves/SIMD -> 6 blocks/CU
//    = 24/32 waves = 75% occupancy (r11 was 47%)
//  - LDS 17KB/block; A-frag duplication 8x -> 4x (LDS reads halved — the
//    fattest pipe at ~33% busy)
//  - cost: W re-read per 32 rows (not 64): +320MB L2, ~10 TB/s, fine.
// Gate: FETCH ~57MB WRITE ~41MB (no scratch), Occ >=70%.
// If dur >= 63us with gate clean: occupancy falsified as the lever ->
// attack in-block phase serialization next.
#include <hip/hip_runtime.h>

typedef __attribute__((ext_vector_type(8))) short short8;
typedef __attribute__((ext_vector_type(8))) unsigned short ushort8;
typedef __attribute__((ext_vector_type(4))) float f32x4;

#define MT 32            // batch rows per block
#define STR 264          // bf16 elems per LDS row: 256 + 8 pad (528B, 16B-aligned)

__device__ __forceinline__ float bmax_r14() { return __uint_as_float(0x7F7F0000u); }

// plain RTNE fp32 -> bf16 bits (pre-epilogue values provably finite/small).
__device__ __forceinline__ unsigned short f2bf_r14(float f) {
    unsigned int u = __float_as_uint(f);
    return (unsigned short)((u + 0x7fffu + ((u >> 16) & 1u)) >> 16);
}

// pack: one thread per 64-lane fragment slot; gathers 8 k-elements and does
// ONE contiguous 16B write. Layout: dst[(frag*64+lane)*8 + j],
// frag=(n>>4)*8+(k>>5), lane=((k>>3)&3)*16+(n&15), j=k&7.
__global__ __launch_bounds__(256)
void pack_weights_r14(const float* __restrict__ W1,
                      const float* __restrict__ W2,
                      const float* __restrict__ W3,
                      unsigned short* __restrict__ ws) {
    int s = blockIdx.x * 256 + threadIdx.x;     // 80 x 256 = 20480 slots
    const float* src;
    unsigned short* dst;
    int N;
    if (s < 8192)       { src = W1; dst = ws;          N = 256; }
    else if (s < 16384) { src = W2; dst = ws + 65536;  N = 256; s -= 8192; }
    else                { src = W3; dst = ws + 131072; N = 128; s -= 16384; }
    int frag = s >> 6, lane = s & 63;
    int kb = (frag & 7) * 32 + (lane >> 4) * 8;   // k base (8 consecutive k)
    int n  = (frag >> 3) * 16 + (lane & 15);
    ushort8 o;
    #pragma unroll
    for (int j = 0; j < 8; ++j) o[j] = f2bf_r14(src[(kb + j) * N + n]);
    *(ushort8*)&dst[s * 8] = o;
}

// One 32x256 dense layer (K=256), bias+relu, bf16 act LDS IN-PLACE.
// Wave w owns col-tiles 4w..4w+3 and ALL 32 rows (2 row-tiles).
__device__ __forceinline__ void layer_mfma_r14(
    const unsigned short* __restrict__ act, const unsigned short* __restrict__ wp,
    int wave, int lane, int quad, int noff, f32x4 acc[2][4])
{
    #pragma unroll
    for (int k0 = 0; k0 < 8; ++k0) {
        short8 b[4];
        #pragma unroll
        for (int ct = 0; ct < 4; ++ct)
            b[ct] = *(const short8*)&wp[(((wave * 4 + ct) * 8 + k0) * 64 + lane) * 8];
        #pragma unroll
        for (int rt = 0; rt < 2; ++rt) {
            short8 a = *(const short8*)&act[(rt * 16 + noff) * STR + k0 * 32 + quad * 8];
            #pragma unroll
            for (int ct = 0; ct < 4; ++ct)
                acc[rt][ct] = __builtin_amdgcn_mfma_f32_16x16x32_bf16(a, b[ct], acc[rt][ct], 0, 0, 0);
        }
    }
}

__device__ __forceinline__ void layer_store_r14(
    unsigned short* __restrict__ act, const float* __restrict__ bias,
    int wave, int quad, int noff, f32x4 acc[2][4])
{
    #pragma unroll
    for (int ct = 0; ct < 4; ++ct) {
        int col = (wave * 4 + ct) * 16 + noff;
        float bv = bias[col];
        #pragma unroll
        for (int rt = 0; rt < 2; ++rt) {
            #pragma unroll
            for (int i = 0; i < 4; ++i) {
                float v = fmaxf(acc[rt][ct][i] + bv, 0.0f);   // relu; finite by data
                act[(rt * 16 + quad * 4 + i) * STR + col] = f2bf_r14(v);
            }
        }
    }
}

__global__ __launch_bounds__(256, 6)   // 6 waves/EU -> cap ~84 regs, 6 blocks/CU
void ColorNetwork_32495722561720_kernel(
        const float* __restrict__ obs,
        const int* __restrict__ amask,
        const float* __restrict__ b1,
        const float* __restrict__ b2,
        const float* __restrict__ b3,
        const unsigned short* __restrict__ w1p,
        const unsigned short* __restrict__ w2p,
        const unsigned short* __restrict__ w3p,
        float* __restrict__ out)
{
    // 16896 (act) + 128 (rowany) = 17024 B LDS -> 6 blocks/CU (reg-capped)
    __shared__ __align__(16) unsigned short act[MT * STR];
    __shared__ int rowany[MT];

    const int tid  = threadIdx.x;
    const int wave = tid >> 6;
    const int lane = tid & 63;
    const int quad = lane >> 4;
    const int noff = lane & 15;
    const size_t rowbase = (size_t)blockIdx.x * MT;

    if (tid < MT) rowany[tid] = 0;

    // ---- stage X: 32 rows x 256 fp32 -> bf16 LDS (2048 float4, 8/thread) ----
    const float4* xin = (const float4*)(obs + rowbase * 256);
    #pragma unroll
    for (int i = 0; i < 8; ++i) {
        int f = tid + i * 256;        // 64 float4-chunks per row
        int row = f >> 6;
        int c4 = f & 63;
        float4 v = xin[f];
        ushort4 p;
        p.x = f2bf_r14(v.x); p.y = f2bf_r14(v.y);
        p.z = f2bf_r14(v.z); p.w = f2bf_r14(v.w);
        *(ushort4*)&act[row * STR + c4 * 4] = p;
    }
    __syncthreads();   // X visible; orders rowany init before |= below

    // ---- rowany (mask words re-read from global in epilogue; L2 absorbs).
    //      32 rows x 128 ints = 1024 int4, 4/thread. ----
    const int4* min4 = (const int4*)(amask + rowbase * 128);
    #pragma unroll
    for (int i = 0; i < 4; ++i) {
        int f = tid + i * 256;
        int4 m = min4[f];
        if (m.x | m.y | m.z | m.w) rowany[f >> 5] = 1;   // 32 int4 per row
    }

    {   // ---- layer 1 (in place) ----
        f32x4 acc[2][4] = {};
        layer_mfma_r14(act, w1p, wave, lane, quad, noff, acc);
        __syncthreads();                       // all reads done (also rowany writes)
        layer_store_r14(act, b1, wave, quad, noff, acc);
        __syncthreads();                       // all writes visible
    }
    {   // ---- layer 2 (in place) ----
        f32x4 acc[2][4] = {};
        layer_mfma_r14(act, w2p, wave, lane, quad, noff, acc);
        __syncthreads();
        layer_store_r14(act, b2, wave, quad, noff, acc);
        __syncthreads();
    }
    {   // ---- layer 3 (N=128): wave owns 2 col-tiles; regs -> masked store ----
        f32x4 acc[2][2] = {};
        #pragma unroll
        for (int k0 = 0; k0 < 8; ++k0) {
            short8 b0 = *(const short8*)&w3p[(((wave * 2 + 0) * 8 + k0) * 64 + lane) * 8];
            short8 b1v = *(const short8*)&w3p[(((wave * 2 + 1) * 8 + k0) * 64 + lane) * 8];
            #pragma unroll
            for (int rt = 0; rt < 2; ++rt) {
                short8 a = *(const short8*)&act[(rt * 16 + noff) * STR + k0 * 32 + quad * 8];
                acc[rt][0] = __builtin_amdgcn_mfma_f32_16x16x32_bf16(a, b0, acc[rt][0], 0, 0, 0);
                acc[rt][1] = __builtin_amdgcn_mfma_f32_16x16x32_bf16(a, b1v, acc[rt][1], 0, 0, 0);
            }
        }

        // mask loads AFTER the MFMAs (L2-hot from the rowany pass); keeping
        // them here holds the live set down — r12's spill lesson.
        const float BM = bmax_r14();
        #pragma unroll
        for (int ct = 0; ct < 2; ++ct) {
            int col = (wave * 2 + ct) * 16 + noff;
            float bv = b3[col];
            #pragma unroll
            for (int rt = 0; rt < 2; ++rt) {
                #pragma unroll
                for (int i = 0; i < 4; ++i) {
                    int row = rt * 16 + quad * 4 + i;
                    int m = amask[(rowbase + row) * 128 + col];
                    float v = acc[rt][ct][i] + bv;
                    v = fminf(fmaxf(v, -BM), BM);        // finite AND bf16-finite
                    if (!(v == v)) v = 0.0f;             // NaN scrub (paranoia)
                    if (!m) v = -BM;                     // FLOAT_MIN stand-in
                    if (!rowany[row]) v = (col == 0) ? 1.0f : -BM;
                    out[(rowbase + row) * 128 + col] = v;
                }
            }
        }
    }
}

extern "C" void kernel_launch(void* const* d_in, const int* in_sizes, int n_in,
                              void* d_out, int out_size, void* d_ws, size_t ws_size,
                              hipStream_t stream) {
    const float* obs   = (const float*)d_in[0];
    const int*   amask = (const int*)d_in[1];
    const float* W1 = (const float*)d_in[2];
    const float* b1 = (const float*)d_in[3];
    const float* W2 = (const float*)d_in[4];
    const float* b2 = (const float*)d_in[5];
    const float* W3 = (const float*)d_in[6];
    const float* b3 = (const float*)d_in[7];
    float* out = (float*)d_out;

    const int B = in_sizes[0] / 256;   // 65536 batch rows

    unsigned short* ws = (unsigned short*)d_ws;    // 163840 bf16 = 320 KB packed
    unsigned short* w1p = ws;
    unsigned short* w2p = ws + 65536;
    unsigned short* w3p = ws + 131072;

    pack_weights_r14<<<80, 256, 0, stream>>>(W1, W2, W3, ws);

    ColorNetwork_32495722561720_kernel<<<B / MT, 256, 0, stream>>>(
        obs, amask, b1, b2, b3, w1p, w2p, w3p, out);
}